// Round 6
// baseline (5802.134 us; speedup 1.0000x reference)
//
#include <hip/hip_runtime.h>

#define NN 30000
#define EE 480000

// ---------- helpers ----------
__device__ __forceinline__ float bfbits(unsigned int u){
  union{unsigned int i; float f;} v; v.i = u<<16; return v.f; }
__device__ __forceinline__ unsigned short f2bf(float f){
  unsigned int x = __float_as_uint(f);
  unsigned int r = (x + 0x7fffu + ((x>>16)&1u)) >> 16;
  return (unsigned short)r;
}
// mode-aware load: md=1 -> f32, md=0 -> bf16
__device__ __forceinline__ float ld(const void* p, size_t i, int md){
  return md ? ((const float*)p)[i]
            : bfbits((unsigned int)((const unsigned short*)p)[i]);
}

// weight scratch offsets (in floats)
#define WO_R1T 0        // [L][32][36]  Wr1 transposed (c-major, j padded to 36)
#define WO_BR1 2304     // [L][32]
#define WO_R2T 2368     // [L][8][32][28]  (cblk, ci, p*4+u)
#define WO_K   16704    // [L][32][32]
#define WO_Q   18752    // [L][32][32]
#define WO_S0  20800
#define WO_S1  22848
#define WO_S2  24896
#define WO_SK  26944
#define WO_OUT 28992    // [32][32]
#define WO_C   30016    // [32][15]
#define WTOT   30496

// ---------- dtype probe: bf16 vs f32 ----------
__global__ void k_detect(const void* pos, unsigned int* modeP){
  unsigned short u = ((const unsigned short*)pos)[threadIdx.x];
  float v = bfbits((unsigned int)u);
  int bad = !(fabsf(v) < 1e4f);          // catches huge + NaN
  unsigned long long m = __ballot(bad);
  if (threadIdx.x==0) modeP[0] = (m!=0ULL) ? 1u : 0u;   // 1 = f32
}

// ---------- zero-fill fallback ----------
__global__ __launch_bounds__(256) void k_zero(float* __restrict__ out, int n){
  int i = blockIdx.x*256 + threadIdx.x;
  if (i < n) out[i] = 0.f;
}

// ---------- weight prep -> f32 wb, edge-kernel-friendly layouts ----------
__global__ __launch_bounds__(256) void k_wprep(
    const void* Wr1, const void* br1, const void* Wr2, const void* Wq,
    const void* Wk,  const void* Ws0, const void* Ws1, const void* Ws2,
    const void* Wsk, const void* Wout, const void* Wc,
    float* __restrict__ wb, const unsigned int* modeP)
{
  int md = (int)modeP[0];
  int t = blockIdx.x*256 + threadIdx.x;
  int st = gridDim.x*256;
  for (int i=t;i<2304;i+=st){ int l=i/1152, r=i%1152, c=r/36, j=r%36;
    wb[WO_R1T+i] = (j<33)? ld(Wr1,(size_t)l*1056 + j*32 + c, md) : 0.f; }
  for (int i=t;i<64;i+=st) wb[WO_BR1+i] = ld(br1,i,md);
  for (int i=t;i<14336;i+=st){ int l=i/7168, r=i%7168, cb=r/896, r2=r%896,
      ci=r2/28, r3=r2%28, p=r3/4, u=r3&3;
    wb[WO_R2T+i] = ld(Wr2,(size_t)l*7168 + ci*224 + p*32 + cb*4 + u, md); }
  for (int i=t;i<2048;i+=st) wb[WO_K+i]  = ld(Wk,i,md);
  for (int i=t;i<2048;i+=st) wb[WO_Q+i]  = ld(Wq,i,md);
  for (int i=t;i<2048;i+=st) wb[WO_S0+i] = ld(Ws0,i,md);
  for (int i=t;i<2048;i+=st) wb[WO_S1+i] = ld(Ws1,i,md);
  for (int i=t;i<2048;i+=st) wb[WO_S2+i] = ld(Ws2,i,md);
  for (int i=t;i<2048;i+=st) wb[WO_SK+i] = ld(Wsk,i,md);
  for (int i=t;i<1024;i+=st) wb[WO_OUT+i]= ld(Wout,i,md);
  for (int i=t;i<480;i+=st)  wb[WO_C+i]  = ld(Wc,i,md);
}

// ---------- node feature init: fA[N][288] (row0=node_l0, rest 0), hist=0 ----------
__global__ __launch_bounds__(256) void k_init(
    const void* nl0, float* __restrict__ fA, int* __restrict__ hist,
    const unsigned int* modeP)
{
  int md = (int)modeP[0];
  int i = blockIdx.x*256 + threadIdx.x;   // exactly N*288
  int n = i/288; int r2 = i - n*288;
  fA[i] = (r2 < 32) ? ld(nl0,(size_t)n*32 + r2, md) : 0.f;
  if (i < NN) hist[i] = 0;
}

__global__ __launch_bounds__(256) void k_hist(const int* __restrict__ dst, int* __restrict__ hist){
  int e = blockIdx.x*256 + threadIdx.x;
  if (e < EE) atomicAdd(&hist[dst[e]], 1);
}

// single-block exclusive scan over hist[NN] -> offs, cursor
__global__ void k_scan(const int* __restrict__ hist, int* __restrict__ offs,
                       int* __restrict__ cursor, int n)
{
  __shared__ int sm[1024];
  __shared__ int carry;
  int tid = threadIdx.x;
  if (tid==0) carry = 0;
  __syncthreads();
  for (int base=0; base<n; base+=1024){
    int i = base + tid;
    int v = (i<n)? hist[i] : 0;
    sm[tid] = v; __syncthreads();
    for (int o=1;o<1024;o<<=1){
      int tv = (tid>=o)? sm[tid-o] : 0;
      __syncthreads();
      sm[tid] += tv;
      __syncthreads();
    }
    int cy = carry;
    int excl = sm[tid] - v;
    if (i<n){ offs[i] = cy+excl; cursor[i] = cy+excl; }
    __syncthreads();
    if (tid==1023) carry = cy + sm[1023];
    __syncthreads();
  }
  if (tid==0) offs[n] = carry;
}

__global__ __launch_bounds__(256) void k_scatter(const int* __restrict__ dst,
    int* __restrict__ cursor, int* __restrict__ perm)
{
  int e = blockIdx.x*256 + threadIdx.x;
  if (e >= EE) return;
  int d = dst[e];
  int p = atomicAdd(&cursor[d], 1);
  perm[p] = e;
}

// ---------- per-node q projection ----------
__global__ __launch_bounds__(256) void k_q(const float* __restrict__ f_in,
    const float* __restrict__ Wqf, float* __restrict__ qn)
{
  int t = blockIdx.x*256 + threadIdx.x;   // N*32 exactly
  int n = t>>5, c = t&31;
  const float* f0 = f_in + (size_t)n*288;
  float acc=0.f;
  #pragma unroll
  for (int ci=0;ci<32;ci++) acc = fmaf(f0[ci], Wqf[ci*32+c], acc);
  qn[t] = acc;
}

// ---------- pass A: per-edge logits (radial MLP -> m0 -> k -> q.k) ----------
__global__ __launch_bounds__(256) void k_edge(
    const void* pos, const void* edge_feat,
    const int* __restrict__ src, const int* __restrict__ dst,
    const float* __restrict__ f_in, const float* __restrict__ qn,
    const float* __restrict__ Wr1t, const float* __restrict__ br1f,
    const float* __restrict__ Wr2t, const float* __restrict__ Wkf,
    float* __restrict__ logitsG, const unsigned int* modeP, int first)
{
  int e = blockIdx.x*256 + threadIdx.x;
  if (e >= EE) return;
  int md = (int)modeP[0];
  int s = src[e], d = dst[e];
  float px = ld(pos,(size_t)d*3+0,md) - ld(pos,(size_t)s*3+0,md);
  float py = ld(pos,(size_t)d*3+1,md) - ld(pos,(size_t)s*3+1,md);
  float pz = ld(pos,(size_t)d*3+2,md) - ld(pos,(size_t)s*3+2,md);
  float r = sqrtf(px*px+py*py+pz*pz+1e-8f);
  float inv = 1.f/r;
  float y1x=px*inv, y1y=py*inv, y1z=pz*inv;
  float y2a=y1x*y1y, y2b=y1y*y1z, y2c=3.f*y1z*y1z-1.f, y2d=y1x*y1z, y2e=y1x*y1x-y1y*y1y;

  float rad[33];
  rad[0]=r;
  #pragma unroll
  for (int i=0;i<32;i++) rad[1+i] = ld(edge_feat,(size_t)e*32+i, md);

  float h[32];
  #pragma unroll
  for (int c=0;c<32;c++){
    float acc = br1f[c];
    #pragma unroll
    for (int j=0;j<33;j++) acc = fmaf(rad[j], Wr1t[c*36+j], acc);
    h[c] = fmaxf(acc, 0.f);
  }

  const float* fs = f_in + (size_t)s*288;
  float kk[32];
  #pragma unroll
  for (int j=0;j<32;j++) kk[j]=0.f;

  #pragma unroll 1
  for (int cb=0; cb<8; cb++){
    const float* W2 = Wr2t + cb*896;
    float w0[4],w1[4],w2[4];
    #pragma unroll
    for (int u=0;u<4;u++){ w0[u]=0;w1[u]=0;w2[u]=0; }
    #pragma unroll
    for (int ci=0; ci<32; ci++){
      float hv = h[ci];
      const float* wr = W2 + ci*28;
      #pragma unroll
      for (int u=0;u<4;u++) w0[u]=fmaf(hv, wr[u], w0[u]);
      if (!first){
        #pragma unroll
        for (int u=0;u<4;u++){
          w1[u]=fmaf(hv, wr[4+u], w1[u]);
          w2[u]=fmaf(hv, wr[8+u], w2[u]);
        }
      }
    }
    int c0 = cb*4;
    float m0[4];
    #pragma unroll
    for (int u=0;u<4;u++){
      float v = w0[u]*fs[c0+u];
      if (!first){
        float g1=0.f, g2=0.f;
        g1 = fs[32 + 0*32 + c0+u]*y1x + fs[32 + 1*32 + c0+u]*y1y + fs[32 + 2*32 + c0+u]*y1z;
        g2 = fs[128 + 0*32 + c0+u]*y2a + fs[128 + 1*32 + c0+u]*y2b + fs[128 + 2*32 + c0+u]*y2c
           + fs[128 + 3*32 + c0+u]*y2d + fs[128 + 4*32 + c0+u]*y2e;
        v += w1[u]*g1 + w2[u]*g2;
      }
      m0[u] = v;
    }
    #pragma unroll
    for (int u=0;u<4;u++){
      float mv = m0[u];
      const float* wk = Wkf + (size_t)(c0+u)*32;
      #pragma unroll
      for (int j=0;j<32;j++) kk[j] = fmaf(mv, wk[j], kk[j]);
    }
  }
  const float* qd = qn + (size_t)d*32;
  #pragma unroll
  for (int hh=0;hh<4;hh++){
    float acc=0.f;
    #pragma unroll
    for (int dh=0;dh<8;dh++) acc = fmaf(qd[hh*8+dh], kk[hh*8+dh], acc);
    logitsG[(size_t)e*4+hh] = acc * 0.35355339059327373f;  // 1/sqrt(8)
  }
}

// ---------- pass B: exact segment softmax -> alphaP at permuted positions ----------
__global__ __launch_bounds__(256) void k_smax(
    const int* __restrict__ offs, const int* __restrict__ perm,
    const float* __restrict__ logitsG, float* __restrict__ alphaP)
{
  int wv = threadIdx.x>>6, lane = threadIdx.x&63;
  int n = blockIdx.x*4 + wv;               // 7500*4 = 30000
  int start = offs[n], end = offs[n+1];
  float m0=-1e30f,m1=-1e30f,m2=-1e30f,m3=-1e30f;
  for (int p=start+lane; p<end; p+=64){
    const float* lg = logitsG + (size_t)perm[p]*4;
    m0=fmaxf(m0,lg[0]); m1=fmaxf(m1,lg[1]); m2=fmaxf(m2,lg[2]); m3=fmaxf(m3,lg[3]);
  }
  #pragma unroll
  for (int mk=1;mk<64;mk<<=1){
    m0=fmaxf(m0,__shfl_xor(m0,mk)); m1=fmaxf(m1,__shfl_xor(m1,mk));
    m2=fmaxf(m2,__shfl_xor(m2,mk)); m3=fmaxf(m3,__shfl_xor(m3,mk));
  }
  float s0=0,s1=0,s2=0,s3=0;
  for (int p=start+lane; p<end; p+=64){
    const float* lg = logitsG + (size_t)perm[p]*4;
    s0 += __expf(lg[0]-m0); s1 += __expf(lg[1]-m1);
    s2 += __expf(lg[2]-m2); s3 += __expf(lg[3]-m3);
  }
  #pragma unroll
  for (int mk=1;mk<64;mk<<=1){
    s0 += __shfl_xor(s0,mk); s1 += __shfl_xor(s1,mk);
    s2 += __shfl_xor(s2,mk); s3 += __shfl_xor(s3,mk);
  }
  float i0=1.f/(s0+1e-8f), i1=1.f/(s1+1e-8f), i2=1.f/(s2+1e-8f), i3=1.f/(s3+1e-8f);
  for (int p=start+lane; p<end; p+=64){
    const float* lg = logitsG + (size_t)perm[p]*4;
    alphaP[(size_t)p*4+0] = __expf(lg[0]-m0)*i0;
    alphaP[(size_t)p*4+1] = __expf(lg[1]-m1)*i1;
    alphaP[(size_t)p*4+2] = __expf(lg[2]-m2)*i2;
    alphaP[(size_t)p*4+3] = __expf(lg[3]-m3)*i3;
  }
}

// ---------- pass C: per node-group (4 nodes, 1 wave) chunked aggregation ----------
__global__ __launch_bounds__(64) void k_agg(
    const void* pos, const void* edge_feat,
    const int* __restrict__ src, const int* __restrict__ dst,
    const int* __restrict__ offs, const int* __restrict__ perm,
    const float* __restrict__ f_in, const float* __restrict__ alphaP,
    const float* __restrict__ Wr1t, const float* __restrict__ br1f,
    const float* __restrict__ Wr2t,
    float* __restrict__ aggG, const unsigned int* modeP, int first)
{
  __shared__ __align__(16) unsigned short msgL[288*66]; // [feature][edge], stride 66
  __shared__ __align__(16) float alL[64*4];             // per-edge alpha (4 heads)

  int t = threadIdx.x;
  int md = (int)modeP[0];
  int n0 = blockIdx.x*4;
  int o0 = offs[n0], o1=offs[n0+1], o2=offs[n0+2], o3=offs[n0+3], o4=offs[n0+4];
  int tc = t & 15, nl = t >> 4;
  int b = tc >> 3;
  int ns = (nl==0)?o0:((nl==1)?o1:((nl==2)?o2:o3));
  int ne = (nl==0)?o1:((nl==1)?o2:((nl==2)?o3:o4));

  float A[18];
  #pragma unroll
  for (int j=0;j<18;j++) A[j]=0.f;

  for (int cs=o0; cs<o4; cs+=64){
    int cnt = o4-cs; if (cnt>64) cnt=64;
    if (t < cnt){
      int p = cs+t;
      int e = perm[p];
      int s = src[e], d = dst[e];
      alL[t*4+0]=alphaP[(size_t)p*4+0]; alL[t*4+1]=alphaP[(size_t)p*4+1];
      alL[t*4+2]=alphaP[(size_t)p*4+2]; alL[t*4+3]=alphaP[(size_t)p*4+3];
      float px = ld(pos,(size_t)d*3+0,md) - ld(pos,(size_t)s*3+0,md);
      float py = ld(pos,(size_t)d*3+1,md) - ld(pos,(size_t)s*3+1,md);
      float pz = ld(pos,(size_t)d*3+2,md) - ld(pos,(size_t)s*3+2,md);
      float r = sqrtf(px*px+py*py+pz*pz+1e-8f);
      float inv = 1.f/r;
      float y1x=px*inv, y1y=py*inv, y1z=pz*inv;
      float y2a=y1x*y1y, y2b=y1y*y1z, y2c=3.f*y1z*y1z-1.f, y2d=y1x*y1z, y2e=y1x*y1x-y1y*y1y;

      float rad[33];
      rad[0]=r;
      #pragma unroll
      for (int i=0;i<32;i++) rad[1+i] = ld(edge_feat,(size_t)e*32+i, md);

      float h[32];
      #pragma unroll
      for (int c=0;c<32;c++){
        float acc = br1f[c];
        #pragma unroll
        for (int j=0;j<33;j++) acc = fmaf(rad[j], Wr1t[c*36+j], acc);
        h[c] = fmaxf(acc, 0.f);
      }

      const float* fs = f_in + (size_t)s*288;
      #pragma unroll 1
      for (int cb=0; cb<8; cb++){
        const float* W2 = Wr2t + cb*896;
        float w0[4],w1[4],w2[4],w3[4],w4[4],w5[4],w6[4];
        #pragma unroll
        for (int u=0;u<4;u++){ w0[u]=0;w1[u]=0;w2[u]=0;w3[u]=0;w4[u]=0;w5[u]=0;w6[u]=0; }
        #pragma unroll
        for (int ci=0; ci<32; ci++){
          float hv = h[ci];
          const float* wr = W2 + ci*28;
          #pragma unroll
          for (int u=0;u<4;u++){
            w0[u]=fmaf(hv, wr[u],    w0[u]);
            w3[u]=fmaf(hv, wr[12+u], w3[u]);
            w5[u]=fmaf(hv, wr[20+u], w5[u]);
          }
          if (!first){
            #pragma unroll
            for (int u=0;u<4;u++){
              w1[u]=fmaf(hv, wr[4+u],  w1[u]);
              w2[u]=fmaf(hv, wr[8+u],  w2[u]);
              w4[u]=fmaf(hv, wr[16+u], w4[u]);
              w6[u]=fmaf(hv, wr[24+u], w6[u]);
            }
          }
        }
        int c0 = cb*4;
        float f0v[4], f1v[3][4], f2v[5][4];
        #pragma unroll
        for (int u=0;u<4;u++) f0v[u] = fs[c0+u];
        if (!first){
          #pragma unroll
          for (int m=0;m<3;m++)
            #pragma unroll
            for (int u=0;u<4;u++) f1v[m][u] = fs[32 + m*32 + c0 + u];
          #pragma unroll
          for (int m=0;m<5;m++)
            #pragma unroll
            for (int u=0;u<4;u++) f2v[m][u] = fs[128 + m*32 + c0 + u];
        } else {
          #pragma unroll
          for (int m=0;m<3;m++){ f1v[m][0]=0;f1v[m][1]=0;f1v[m][2]=0;f1v[m][3]=0; }
          #pragma unroll
          for (int m=0;m<5;m++){ f2v[m][0]=0;f2v[m][1]=0;f2v[m][2]=0;f2v[m][3]=0; }
        }
        #pragma unroll
        for (int u=0;u<4;u++){
          float v = w0[u]*f0v[u];
          if (!first){
            float g1 = f1v[0][u]*y1x + f1v[1][u]*y1y + f1v[2][u]*y1z;
            float g2 = f2v[0][u]*y2a + f2v[1][u]*y2b + f2v[2][u]*y2c + f2v[3][u]*y2d + f2v[4][u]*y2e;
            v += w1[u]*g1 + w2[u]*g2;
          }
          msgL[(c0+u)*66 + t] = f2bf(v);
        }
        #pragma unroll
        for (int m=0;m<3;m++){
          float ym = (m==0)?y1x:((m==1)?y1y:y1z);
          #pragma unroll
          for (int u=0;u<4;u++){
            float tv = w3[u]*f0v[u]*ym;
            if (!first) tv += w4[u]*f1v[m][u];
            msgL[((1+m)*32 + c0+u)*66 + t] = f2bf(tv);
          }
        }
        #pragma unroll
        for (int m=0;m<5;m++){
          float ym = (m==0)?y2a:((m==1)?y2b:((m==2)?y2c:((m==3)?y2d:y2e)));
          #pragma unroll
          for (int u=0;u<4;u++){
            float tv = w5[u]*f0v[u]*ym;
            if (!first) tv += w6[u]*f2v[m][u];
            msgL[((4+m)*32 + c0+u)*66 + t] = f2bf(tv);
          }
        }
      }
    }
    __syncthreads();

    int li = (ns>cs)? ns-cs : 0;
    int hi = ((ne < cs+cnt)? ne : cs+cnt) - cs;
    for (int e2=li; e2<hi; ++e2){
      float wEv = alL[e2*4 + b];
      float wOd = alL[e2*4 + b + 2];
      #pragma unroll
      for (int j=0;j<18;j++){
        float mv = bfbits((unsigned int)msgL[(tc+16*j)*66 + e2]);
        A[j] = fmaf((j&1)?wOd:wEv, mv, A[j]);
      }
    }
    __syncthreads();
  }
  int n = n0 + nl;
  #pragma unroll
  for (int j=0;j<18;j++)
    aggG[(size_t)n*288 + tc + 16*j] = A[j];
}

// ---------- node update: f_out = [agg0@Ws0 + f0@Wsk, agg1@Ws1, agg2@Ws2] ----------
__global__ __launch_bounds__(256) void k_update(
    const float* __restrict__ aggG, const float* __restrict__ f_in,
    const float* __restrict__ Ws0, const float* __restrict__ Ws1,
    const float* __restrict__ Ws2, const float* __restrict__ Wsk,
    float* __restrict__ f_out)
{
  __shared__ float wL[4096];
  __shared__ float agL[8][297];
  __shared__ float f0L[8][33];
  int tid = threadIdx.x;
  int nb = blockIdx.x*8;
  for (int i=tid;i<1024;i+=256){
    wL[i]=Ws0[i]; wL[1024+i]=Ws1[i]; wL[2048+i]=Ws2[i]; wL[3072+i]=Wsk[i];
  }
  for (int i=tid;i<2304;i+=256){
    int nl=i/288, F=i-nl*288, r=F>>5, c=F&31;
    agL[nl][r*33+c] = aggG[(size_t)(nb+nl)*288 + F];
  }
  if (tid<256){ int nl=tid>>5, c=tid&31; f0L[nl][c] = f_in[(size_t)(nb+nl)*288 + c]; }
  __syncthreads();
  int nl = tid>>5, o = tid&31;
  size_t obase = (size_t)(nb+nl)*288;
  #pragma unroll 1
  for (int r=0;r<9;r++){
    const float* W = (r==0)? wL : ((r<4)? wL+1024 : wL+2048);
    float acc=0.f;
    #pragma unroll
    for (int c=0;c<32;c++) acc = fmaf(agL[nl][r*33+c], W[c*32+o], acc);
    if (r==0){
      #pragma unroll
      for (int c=0;c<32;c++) acc = fmaf(f0L[nl][c], wL[3072 + c*32+o], acc);
    }
    f_out[obase + r*32 + o] = acc;
  }
}

// ---------- output head: FLOAT32 output (reference output dtype is float32) ----------
__global__ __launch_bounds__(256) void k_out(
    const float* __restrict__ f_in, const float* __restrict__ Wout,
    const float* __restrict__ Wc, float* __restrict__ out)
{
  __shared__ float sh[8][33];
  int tid = threadIdx.x;
  int nl = tid>>5, c = tid&31;
  int n = blockIdx.x*8 + nl;
  const float* f0 = f_in + (size_t)n*288;
  float acc=0.f;
  #pragma unroll
  for (int ci=0;ci<32;ci++) acc = fmaf(f0[ci], Wout[ci*32+c], acc);
  out[(size_t)n*32 + c] = acc;
  sh[nl][c] = acc;
  __syncthreads();
  if (tid < 120){
    int nl2 = tid/15, j = tid%15;
    int n2 = blockIdx.x*8 + nl2;
    float a = 0.f;
    #pragma unroll
    for (int ci=0;ci<32;ci++) a = fmaf(sh[nl2][ci], Wc[ci*15+j], a);
    out[(size_t)NN*32 + (size_t)n2*15 + j] = a;
  }
}

extern "C" void kernel_launch(void* const* d_in, const int* in_sizes, int n_in,
                              void* d_out, int out_size, void* d_ws, size_t ws_size,
                              hipStream_t stream)
{
  (void)in_sizes; (void)n_in;
  const void* pos       = d_in[0];
  const void* node_l0   = d_in[1];
  const void* edge_feat = d_in[2];
  const int* esrc = (const int*)d_in[3];
  const int* edst = (const int*)d_in[4];

  char* ws = (char*)d_ws;
  size_t off = 0;
  auto take = [&](size_t bytes)->char*{
    char* p = ws + off;
    off += (bytes + 255) & ~(size_t)255;
    return p;
  };
  float* fA      = (float*)take((size_t)NN*288*4);
  float* fB      = (float*)take((size_t)NN*288*4);
  float* qn      = (float*)take((size_t)NN*32*4);
  int*   hist    = (int*)  take((size_t)NN*4);
  int*   offs    = (int*)  take((size_t)(NN+1)*4);
  int*   cursor  = (int*)  take((size_t)NN*4);
  int*   perm    = (int*)  take((size_t)EE*4);
  float* wb      = (float*)take((size_t)WTOT*4);
  float* logitsG = (float*)take((size_t)EE*4*4);
  float* alphaP  = (float*)take((size_t)EE*4*4);
  unsigned int* modeP = (unsigned int*)take(256);
  size_t need = off;                                 // ~91 MB

  if (ws_size < need){
    k_zero<<<(out_size+255)/256,256,0,stream>>>((float*)d_out, out_size);
    return;
  }

  k_detect<<<1,64,0,stream>>>(pos, modeP);
  k_wprep<<<64,256,0,stream>>>(d_in[5],d_in[6],d_in[7],d_in[8],d_in[9],d_in[10],
                               d_in[11],d_in[12],d_in[13],d_in[14],d_in[15], wb, modeP);
  k_init<<<33750,256,0,stream>>>(node_l0, fA, hist, modeP);
  k_hist<<<1875,256,0,stream>>>(edst, hist);
  k_scan<<<1,1024,0,stream>>>(hist, offs, cursor, NN);
  k_scatter<<<1875,256,0,stream>>>(edst, cursor, perm);

  float* fi = fA; float* fo = fB;
  for (int l=0; l<2; ++l){
    int first = (l==0)?1:0;
    k_q<<<3750,256,0,stream>>>(fi, wb+WO_Q + l*1024, qn);
    k_edge<<<1875,256,0,stream>>>(pos, edge_feat, esrc, edst, fi, qn,
        wb+WO_R1T + l*1152, wb+WO_BR1 + l*32,
        wb+WO_R2T + l*7168, wb+WO_K + l*1024,
        logitsG, modeP, first);
    k_smax<<<7500,256,0,stream>>>(offs, perm, logitsG, alphaP);
    k_agg<<<7500,64,0,stream>>>(pos, edge_feat, esrc, edst, offs, perm,
        fi, alphaP,
        wb+WO_R1T + l*1152, wb+WO_BR1 + l*32,
        wb+WO_R2T + l*7168,
        fo, modeP, first);
    k_update<<<3750,256,0,stream>>>(fo, fi,
        wb+WO_S0 + l*1024, wb+WO_S1 + l*1024,
        wb+WO_S2 + l*1024, wb+WO_SK + l*1024, fo);
    float* tmp = fi; fi = fo; fo = tmp;
  }
  k_out<<<3750,256,0,stream>>>(fi, wb+WO_OUT, wb+WO_C, (float*)d_out);
}

// Round 7
// 3074.786 us; speedup vs baseline: 1.8870x; 1.8870x over previous
//
#include <hip/hip_runtime.h>

#define NN 30000
#define EE 480000

// ---------- zero-fill fallback (ws too small diagnostic) ----------
__global__ __launch_bounds__(256) void k_zero(float* __restrict__ out, int n){
  int i = blockIdx.x*256 + threadIdx.x;
  if (i < n) out[i] = 0.f;
}

// ---------- node feature init: fA[N][288] (row0=node_l0, rest 0), hist=0 ----------
__global__ __launch_bounds__(256) void k_init(
    const float* __restrict__ nl0, float* __restrict__ fA, int* __restrict__ hist)
{
  int i = blockIdx.x*256 + threadIdx.x;   // exactly N*288
  int n = i/288; int r2 = i - n*288;
  fA[i] = (r2 < 32) ? nl0[(size_t)n*32 + r2] : 0.f;
  if (i < NN) hist[i] = 0;
}

__global__ __launch_bounds__(256) void k_hist(const int* __restrict__ dst, int* __restrict__ hist){
  int e = blockIdx.x*256 + threadIdx.x;
  if (e < EE) atomicAdd(&hist[dst[e]], 1);
}

// single-block exclusive scan over hist[NN] -> offs, cursor
__global__ void k_scan(const int* __restrict__ hist, int* __restrict__ offs,
                       int* __restrict__ cursor, int n)
{
  __shared__ int sm[1024];
  __shared__ int carry;
  int tid = threadIdx.x;
  if (tid==0) carry = 0;
  __syncthreads();
  for (int base=0; base<n; base+=1024){
    int i = base + tid;
    int v = (i<n)? hist[i] : 0;
    sm[tid] = v; __syncthreads();
    for (int o=1;o<1024;o<<=1){
      int tv = (tid>=o)? sm[tid-o] : 0;
      __syncthreads();
      sm[tid] += tv;
      __syncthreads();
    }
    int cy = carry;
    int excl = sm[tid] - v;
    if (i<n){ offs[i] = cy+excl; cursor[i] = cy+excl; }
    __syncthreads();
    if (tid==1023) carry = cy + sm[1023];
    __syncthreads();
  }
  if (tid==0) offs[n] = carry;
}

__global__ __launch_bounds__(256) void k_scatter(const int* __restrict__ dst,
    int* __restrict__ cursor, int* __restrict__ perm)
{
  int e = blockIdx.x*256 + threadIdx.x;
  if (e >= EE) return;
  int d = dst[e];
  int p = atomicAdd(&cursor[d], 1);
  perm[p] = e;
}

// ---------- per-node q projection ----------
__global__ __launch_bounds__(256) void k_q(const float* __restrict__ f_in,
    const float* __restrict__ Wqf, float* __restrict__ qn)
{
  int t = blockIdx.x*256 + threadIdx.x;   // N*32 exactly
  int n = t>>5, c = t&31;
  const float* f0 = f_in + (size_t)n*288;
  float acc=0.f;
  #pragma unroll
  for (int ci=0;ci<32;ci++) acc = fmaf(f0[ci], Wqf[ci*32+c], acc);
  qn[t] = acc;
}

// ---------- pass A: channel-parallel per-edge logits ----------
// half-wave (32 lanes) = 1 edge, lane c = channel c. Processed in perm (dst-sorted)
// order; logits written CONTIGUOUSLY at permuted position p.
// block = 256 threads = 4 waves; each wave does 16 edges -> 64 edges/block.
__global__ __launch_bounds__(256) void k_edge(
    const float* __restrict__ pos, const float* __restrict__ ef,
    const int* __restrict__ src, const int* __restrict__ dst,
    const int* __restrict__ perm,
    const float* __restrict__ f_in, const float* __restrict__ qn,
    const float* __restrict__ Wr1g, const float* __restrict__ br1g,
    const float* __restrict__ Wr2g, const float* __restrict__ Wkg,
    float* __restrict__ logitsP, int first)
{
  __shared__ float W1L[1056];   // [33][32]
  __shared__ float W2L[7168];   // [32][224]
  __shared__ float WKL[1024];   // [32][32]
  __shared__ float B1L[32];
  int tid = threadIdx.x;
  for (int i=tid;i<1056;i+=256) W1L[i]=Wr1g[i];
  for (int i=tid;i<7168;i+=256) W2L[i]=Wr2g[i];
  for (int i=tid;i<1024;i+=256) WKL[i]=Wkg[i];
  if (tid<32) B1L[tid]=br1g[tid];
  __syncthreads();

  int lane = tid & 63;
  int wv   = tid >> 6;
  int c    = lane & 31;
  int half = lane >> 5;
  int hh   = c >> 3;
  int base = blockIdx.x*64 + wv*16;      // 7500 blocks * 64 = 480000 exact

  #pragma unroll 1
  for (int it=0; it<8; ++it){
    int p = base + it*2 + half;
    int e = perm[p];
    int s = src[e], d = dst[e];
    float px = pos[d*3+0]-pos[s*3+0];
    float py = pos[d*3+1]-pos[s*3+1];
    float pz = pos[d*3+2]-pos[s*3+2];
    float rr = sqrtf(px*px+py*py+pz*pz+1e-8f);
    float inv = 1.f/rr;
    float y1x=px*inv, y1y=py*inv, y1z=pz*inv;
    float y2a=y1x*y1y, y2b=y1y*y1z, y2c=3.f*y1z*y1z-1.f, y2d=y1x*y1z, y2e=y1x*y1x-y1y*y1y;

    float rv = ef[(size_t)e*32 + c];                 // coalesced 128B row
    float h = B1L[c] + rr*W1L[c];
    #pragma unroll
    for (int j=0;j<32;j++) h = fmaf(__shfl(rv,j,32), W1L[(1+j)*32+c], h);
    h = fmaxf(h, 0.f);

    float w0=0.f, w1=0.f, w2=0.f;
    #pragma unroll
    for (int ci=0;ci<32;ci++){
      float hb = __shfl(h,ci,32);
      const float* wr = &W2L[ci*224 + c];
      w0 = fmaf(hb, wr[0],  w0);
      if (!first){
        w1 = fmaf(hb, wr[32], w1);
        w2 = fmaf(hb, wr[64], w2);
      }
    }
    const float* fs = f_in + (size_t)s*288;
    float m0 = w0 * fs[c];
    if (!first){
      float g1 = fs[32+c]*y1x + fs[64+c]*y1y + fs[96+c]*y1z;
      float g2 = fs[128+c]*y2a + fs[160+c]*y2b + fs[192+c]*y2c + fs[224+c]*y2d + fs[256+c]*y2e;
      m0 += w1*g1 + w2*g2;
    }
    float kk = 0.f;
    #pragma unroll
    for (int ci=0;ci<32;ci++) kk = fmaf(__shfl(m0,ci,32), WKL[ci*32+c], kk);

    float pr = qn[(size_t)d*32 + c] * kk;
    pr += __shfl_xor(pr,1,8); pr += __shfl_xor(pr,2,8); pr += __shfl_xor(pr,4,8);
    if ((c&7)==0) logitsP[(size_t)p*4 + hh] = pr * 0.35355339059327373f; // 1/sqrt(8)
  }
}

// ---------- pass B: per-node softmax + channel-parallel aggregation ----------
// wave = 1 dst node; 2 edges per iteration (half-wave each, lane c = channel).
// Softmax stats in registers (exact: contiguous logitsP slice), then a-weighted
// message recompute+accumulate in f32.
__global__ __launch_bounds__(256) void k_agg(
    const float* __restrict__ pos, const float* __restrict__ ef,
    const int* __restrict__ src, const int* __restrict__ dst,
    const int* __restrict__ offs, const int* __restrict__ perm,
    const float* __restrict__ f_in, const float* __restrict__ logitsP,
    const float* __restrict__ Wr1g, const float* __restrict__ br1g,
    const float* __restrict__ Wr2g,
    float* __restrict__ aggG, int first)
{
  __shared__ float W1L[1056];
  __shared__ float W2L[7168];
  __shared__ float B1L[32];
  int tid = threadIdx.x;
  for (int i=tid;i<1056;i+=256) W1L[i]=Wr1g[i];
  for (int i=tid;i<7168;i+=256) W2L[i]=Wr2g[i];
  if (tid<32) B1L[tid]=br1g[tid];
  __syncthreads();

  int lane = tid & 63;
  int wv   = tid >> 6;
  int c    = lane & 31;
  int half = lane >> 5;
  int hh   = c >> 3;
  int n = blockIdx.x*4 + wv;             // 7500*4 = 30000 exact
  int start = offs[n], end = offs[n+1];

  // exact segment softmax stats (coalesced float4 reads of contiguous slice)
  float m0=-1e30f,m1=-1e30f,m2=-1e30f,m3=-1e30f;
  for (int p=start+lane;p<end;p+=64){
    float4 lv = *(const float4*)(logitsP + (size_t)p*4);
    m0=fmaxf(m0,lv.x); m1=fmaxf(m1,lv.y); m2=fmaxf(m2,lv.z); m3=fmaxf(m3,lv.w);
  }
  #pragma unroll
  for (int mk=1;mk<64;mk<<=1){
    m0=fmaxf(m0,__shfl_xor(m0,mk)); m1=fmaxf(m1,__shfl_xor(m1,mk));
    m2=fmaxf(m2,__shfl_xor(m2,mk)); m3=fmaxf(m3,__shfl_xor(m3,mk));
  }
  float s0=0.f,s1=0.f,s2=0.f,s3=0.f;
  for (int p=start+lane;p<end;p+=64){
    float4 lv = *(const float4*)(logitsP + (size_t)p*4);
    s0 += __expf(lv.x-m0); s1 += __expf(lv.y-m1);
    s2 += __expf(lv.z-m2); s3 += __expf(lv.w-m3);
  }
  #pragma unroll
  for (int mk=1;mk<64;mk<<=1){
    s0 += __shfl_xor(s0,mk); s1 += __shfl_xor(s1,mk);
    s2 += __shfl_xor(s2,mk); s3 += __shfl_xor(s3,mk);
  }
  float i0=1.f/(s0+1e-8f), i1=1.f/(s1+1e-8f), i2=1.f/(s2+1e-8f), i3=1.f/(s3+1e-8f);
  float mh = (hh==0)?m0:((hh==1)?m1:((hh==2)?m2:m3));
  float ih = (hh==0)?i0:((hh==1)?i1:((hh==2)?i2:i3));

  float A[9];
  #pragma unroll
  for (int j=0;j<9;j++) A[j]=0.f;

  #pragma unroll 1
  for (int p0=start; p0<end; p0+=2){
    int p = p0 + half;
    bool act = (p < end);
    int pe = act ? p : start;            // valid dummy for inactive half
    int e = perm[pe];
    int s = src[e], d = dst[e];
    float px = pos[d*3+0]-pos[s*3+0];
    float py = pos[d*3+1]-pos[s*3+1];
    float pz = pos[d*3+2]-pos[s*3+2];
    float rr = sqrtf(px*px+py*py+pz*pz+1e-8f);
    float inv = 1.f/rr;
    float y1x=px*inv, y1y=py*inv, y1z=pz*inv;
    float y2a=y1x*y1y, y2b=y1y*y1z, y2c=3.f*y1z*y1z-1.f, y2d=y1x*y1z, y2e=y1x*y1x-y1y*y1y;

    float rv = ef[(size_t)e*32 + c];
    float h = B1L[c] + rr*W1L[c];
    #pragma unroll
    for (int j=0;j<32;j++) h = fmaf(__shfl(rv,j,32), W1L[(1+j)*32+c], h);
    h = fmaxf(h, 0.f);

    float w0=0.f,w1=0.f,w2=0.f,w3=0.f,w4=0.f,w5=0.f,w6=0.f;
    #pragma unroll
    for (int ci=0;ci<32;ci++){
      float hb = __shfl(h,ci,32);
      const float* wr = &W2L[ci*224 + c];
      w0 = fmaf(hb, wr[0],   w0);
      w3 = fmaf(hb, wr[96],  w3);
      w5 = fmaf(hb, wr[160], w5);
      if (!first){
        w1 = fmaf(hb, wr[32],  w1);
        w2 = fmaf(hb, wr[64],  w2);
        w4 = fmaf(hb, wr[128], w4);
        w6 = fmaf(hb, wr[192], w6);
      }
    }
    const float* fs = f_in + (size_t)s*288;
    float f0 = fs[c];
    float f1a=0.f,f1b=0.f,f1c=0.f, f2a=0.f,f2b=0.f,f2c=0.f,f2d=0.f,f2e=0.f;
    if (!first){
      f1a=fs[32+c]; f1b=fs[64+c]; f1c=fs[96+c];
      f2a=fs[128+c]; f2b=fs[160+c]; f2c=fs[192+c]; f2d=fs[224+c]; f2e=fs[256+c];
    }
    float m0v = w0*f0;
    if (!first){
      m0v += w1*(f1a*y1x+f1b*y1y+f1c*y1z)
           + w2*(f2a*y2a+f2b*y2b+f2c*y2c+f2d*y2d+f2e*y2e);
    }
    float lgv = logitsP[(size_t)pe*4 + hh];
    float a = act ? (__expf(lgv - mh) * ih) : 0.f;

    A[0] = fmaf(a, m0v, A[0]);
    A[1] = fmaf(a, w3*f0*y1x + w4*f1a, A[1]);
    A[2] = fmaf(a, w3*f0*y1y + w4*f1b, A[2]);
    A[3] = fmaf(a, w3*f0*y1z + w4*f1c, A[3]);
    A[4] = fmaf(a, w5*f0*y2a + w6*f2a, A[4]);
    A[5] = fmaf(a, w5*f0*y2b + w6*f2b, A[5]);
    A[6] = fmaf(a, w5*f0*y2c + w6*f2c, A[6]);
    A[7] = fmaf(a, w5*f0*y2d + w6*f2d, A[7]);
    A[8] = fmaf(a, w5*f0*y2e + w6*f2e, A[8]);
  }
  #pragma unroll
  for (int j=0;j<9;j++) A[j] += __shfl_xor(A[j],32,64);
  if (half==0){
    #pragma unroll
    for (int j=0;j<9;j++) aggG[(size_t)n*288 + j*32 + c] = A[j];
  }
}

// ---------- node update: f_out = [agg0@Ws0 + f0@Wsk, agg1@Ws1, agg2@Ws2] ----------
__global__ __launch_bounds__(256) void k_update(
    const float* __restrict__ aggG, const float* __restrict__ f_in,
    const float* __restrict__ Ws0, const float* __restrict__ Ws1,
    const float* __restrict__ Ws2, const float* __restrict__ Wsk,
    float* __restrict__ f_out)
{
  __shared__ float wL[4096];
  __shared__ float agL[8][297];
  __shared__ float f0L[8][33];
  int tid = threadIdx.x;
  int nb = blockIdx.x*8;
  for (int i=tid;i<1024;i+=256){
    wL[i]=Ws0[i]; wL[1024+i]=Ws1[i]; wL[2048+i]=Ws2[i]; wL[3072+i]=Wsk[i];
  }
  for (int i=tid;i<2304;i+=256){
    int nl=i/288, F=i-nl*288, r=F>>5, cc=F&31;
    agL[nl][r*33+cc] = aggG[(size_t)(nb+nl)*288 + F];
  }
  { int nl=tid>>5, cc=tid&31; f0L[nl][cc] = f_in[(size_t)(nb+nl)*288 + cc]; }
  __syncthreads();
  int nl = tid>>5, o = tid&31;
  size_t obase = (size_t)(nb+nl)*288;
  #pragma unroll 1
  for (int r=0;r<9;r++){
    const float* W = (r==0)? wL : ((r<4)? wL+1024 : wL+2048);
    float acc=0.f;
    #pragma unroll
    for (int cc=0;cc<32;cc++) acc = fmaf(agL[nl][r*33+cc], W[cc*32+o], acc);
    if (r==0){
      #pragma unroll
      for (int cc=0;cc<32;cc++) acc = fmaf(f0L[nl][cc], wL[3072 + cc*32+o], acc);
    }
    f_out[obase + r*32 + o] = acc;
  }
}

// ---------- output head (f32 out) ----------
__global__ __launch_bounds__(256) void k_out(
    const float* __restrict__ f_in, const float* __restrict__ Wout,
    const float* __restrict__ Wc, float* __restrict__ out)
{
  __shared__ float sh[8][33];
  int tid = threadIdx.x;
  int nl = tid>>5, c = tid&31;
  int n = blockIdx.x*8 + nl;
  const float* f0 = f_in + (size_t)n*288;
  float acc=0.f;
  #pragma unroll
  for (int ci=0;ci<32;ci++) acc = fmaf(f0[ci], Wout[ci*32+c], acc);
  out[(size_t)n*32 + c] = acc;
  sh[nl][c] = acc;
  __syncthreads();
  if (tid < 120){
    int nl2 = tid/15, j = tid%15;
    int n2 = blockIdx.x*8 + nl2;
    float a = 0.f;
    #pragma unroll
    for (int ci=0;ci<32;ci++) a = fmaf(sh[nl2][ci], Wc[ci*15+j], a);
    out[(size_t)NN*32 + (size_t)n2*15 + j] = a;
  }
}

extern "C" void kernel_launch(void* const* d_in, const int* in_sizes, int n_in,
                              void* d_out, int out_size, void* d_ws, size_t ws_size,
                              hipStream_t stream)
{
  (void)in_sizes; (void)n_in;
  const float* pos       = (const float*)d_in[0];
  const float* node_l0   = (const float*)d_in[1];
  const float* edge_feat = (const float*)d_in[2];
  const int* esrc = (const int*)d_in[3];
  const int* edst = (const int*)d_in[4];
  const float* Wr1  = (const float*)d_in[5];
  const float* br1  = (const float*)d_in[6];
  const float* Wr2  = (const float*)d_in[7];
  const float* Wq   = (const float*)d_in[8];
  const float* Wk   = (const float*)d_in[9];
  const float* Ws0  = (const float*)d_in[10];
  const float* Ws1  = (const float*)d_in[11];
  const float* Ws2  = (const float*)d_in[12];
  const float* Wsk  = (const float*)d_in[13];
  const float* Wout = (const float*)d_in[14];
  const float* Wc   = (const float*)d_in[15];

  char* ws = (char*)d_ws;
  size_t off = 0;
  auto take = [&](size_t bytes)->char*{
    char* p = ws + off;
    off += (bytes + 255) & ~(size_t)255;
    return p;
  };
  float* fA      = (float*)take((size_t)NN*288*4);   // 34.56 MB
  float* fB      = (float*)take((size_t)NN*288*4);   // 34.56 MB
  float* qn      = (float*)take((size_t)NN*32*4);    //  3.84 MB
  int*   hist    = (int*)  take((size_t)NN*4);
  int*   offs    = (int*)  take((size_t)(NN+1)*4);
  int*   cursor  = (int*)  take((size_t)NN*4);
  int*   perm    = (int*)  take((size_t)EE*4);       //  1.92 MB
  float* logitsP = (float*)take((size_t)EE*4*4);     //  7.68 MB
  size_t need = off;                                  // ~83 MB (R6 proved >=91 OK)

  if (ws_size < need){
    k_zero<<<(out_size+255)/256,256,0,stream>>>((float*)d_out, out_size);
    return;
  }

  k_init<<<33750,256,0,stream>>>(node_l0, fA, hist);
  k_hist<<<1875,256,0,stream>>>(edst, hist);
  k_scan<<<1,1024,0,stream>>>(hist, offs, cursor, NN);
  k_scatter<<<1875,256,0,stream>>>(edst, cursor, perm);

  float* fi = fA; float* fo = fB;
  for (int l=0; l<2; ++l){
    int first = (l==0)?1:0;
    k_q<<<3750,256,0,stream>>>(fi, Wq + l*1024, qn);
    k_edge<<<7500,256,0,stream>>>(pos, edge_feat, esrc, edst, perm,
        fi, qn,
        Wr1 + l*1056, br1 + l*32, Wr2 + l*7168, Wk + l*1024,
        logitsP, first);
    k_agg<<<7500,256,0,stream>>>(pos, edge_feat, esrc, edst, offs, perm,
        fi, logitsP,
        Wr1 + l*1056, br1 + l*32, Wr2 + l*7168,
        fo, first);
    k_update<<<3750,256,0,stream>>>(fo, fi,
        Ws0 + l*1024, Ws1 + l*1024, Ws2 + l*1024, Wsk + l*1024, fo);
    float* tmp = fi; fi = fo; fo = tmp;
  }
  k_out<<<3750,256,0,stream>>>(fi, Wout, Wc, (float*)d_out);
}